// Round 8
// baseline (1006.385 us; speedup 1.0000x reference)
//
#include <hip/hip_runtime.h>

#define NV 100000
#define NC 100000
#define NSOC 20000
#define NVS (NV + NSOC)
#define EVC 2000000
#define ESC 300000
#define H 64

constexpr int BSH = 7;       // 128 nodes per bucket
constexpr int NBMAX = 1024;  // max buckets
constexpr int EPB = 8192;    // edges per block in bucket passes
constexpr int TR = 64;       // rows per block in GEMM-ish kernels

// ===========================================================================
// Shared device helpers for phase-fused kernels.
// Each wave owns rows [r0, r0+16) of the LDS tiles; phases reload ONE pair of
// weight arrays (<=128 VGPR live) -- round-5 lesson: 4 live sets => spill.
// ===========================================================================
__device__ __forceinline__ void stage_tile(const float* __restrict__ X, float* s,
                                           int n0, int N, int tid) {
  const float4* X4 = reinterpret_cast<const float4*>(X);
  float4* S4 = reinterpret_cast<float4*>(s);
  const long base4 = (long)n0 * (H / 4);
  const long lim4 = (long)N * (H / 4);
  for (int i = tid; i < TR * H / 4; i += 256)
    S4[i] = (base4 + i < lim4) ? X4[base4 + i] : make_float4(0.f, 0.f, 0.f, 0.f);
}

// sh_row = relu( s1*(sh_row@Wself + bias) + sa_row@Wneigh ), in place.
__device__ __forceinline__ void apply_layer_inplace(
    float* sh, const float* sa,
    const float* __restrict__ Wself, const float* __restrict__ Wneigh,
    const float* __restrict__ bias, int lane, int r0, float s1)
{
  float ws[H], wn[H];
#pragma unroll
  for (int k = 0; k < H; ++k) ws[k] = Wself[k * H + lane];
#pragma unroll
  for (int k = 0; k < H; ++k) wn[k] = Wneigh[k * H + lane];
  const float bj = bias[lane];
  for (int i = 0; i < 16; i += 2) {
    const float4* xa = reinterpret_cast<const float4*>(sh + (r0 + i) * H);
    const float4* xb = reinterpret_cast<const float4*>(sh + (r0 + i + 1) * H);
    float a0 = 0.f, a1 = 0.f, a2 = 0.f, a3 = 0.f;
    float b0 = 0.f, b1 = 0.f, b2 = 0.f, b3 = 0.f;
#pragma unroll
    for (int k4 = 0; k4 < H / 4; ++k4) {
      const float4 va = xa[k4], vb = xb[k4];
      a0 = fmaf(va.x, ws[4 * k4 + 0], a0); b0 = fmaf(vb.x, ws[4 * k4 + 0], b0);
      a1 = fmaf(va.y, ws[4 * k4 + 1], a1); b1 = fmaf(vb.y, ws[4 * k4 + 1], b1);
      a2 = fmaf(va.z, ws[4 * k4 + 2], a2); b2 = fmaf(vb.z, ws[4 * k4 + 2], b2);
      a3 = fmaf(va.w, ws[4 * k4 + 3], a3); b3 = fmaf(vb.w, ws[4 * k4 + 3], b3);
    }
    float accA = s1 * (((a0 + a1) + (a2 + a3)) + bj);
    float accB = s1 * (((b0 + b1) + (b2 + b3)) + bj);
    const float4* ya = reinterpret_cast<const float4*>(sa + (r0 + i) * H);
    const float4* yb = reinterpret_cast<const float4*>(sa + (r0 + i + 1) * H);
    a0 = 0.f; a1 = 0.f; a2 = 0.f; a3 = 0.f;
    b0 = 0.f; b1 = 0.f; b2 = 0.f; b3 = 0.f;
#pragma unroll
    for (int k4 = 0; k4 < H / 4; ++k4) {
      const float4 va = ya[k4], vb = yb[k4];
      a0 = fmaf(va.x, wn[4 * k4 + 0], a0); b0 = fmaf(vb.x, wn[4 * k4 + 0], b0);
      a1 = fmaf(va.y, wn[4 * k4 + 1], a1); b1 = fmaf(vb.y, wn[4 * k4 + 1], b1);
      a2 = fmaf(va.z, wn[4 * k4 + 2], a2); b2 = fmaf(vb.z, wn[4 * k4 + 2], b2);
      a3 = fmaf(va.w, wn[4 * k4 + 3], a3); b3 = fmaf(vb.w, wn[4 * k4 + 3], b3);
    }
    accA += (a0 + a1) + (a2 + a3);
    accB += (b0 + b1) + (b2 + b3);
    sh[(r0 + i) * H + lane] = fmaxf(accA, 0.f);
    sh[(r0 + i + 1) * H + lane] = fmaxf(accB, 0.f);
  }
}

// sh_row = relu(sh_row@W + b), in place (MLP hidden layer).
__device__ __forceinline__ void apply_lin_inplace(
    float* sh, const float* __restrict__ W, const float* __restrict__ b,
    int lane, int r0)
{
  float w[H];
#pragma unroll
  for (int k = 0; k < H; ++k) w[k] = W[k * H + lane];
  const float bj = b[lane];
  for (int i = 0; i < 16; i += 2) {
    const float4* xa = reinterpret_cast<const float4*>(sh + (r0 + i) * H);
    const float4* xb = reinterpret_cast<const float4*>(sh + (r0 + i + 1) * H);
    float a0 = 0.f, a1 = 0.f, a2 = 0.f, a3 = 0.f;
    float b0 = 0.f, b1 = 0.f, b2 = 0.f, b3 = 0.f;
#pragma unroll
    for (int k4 = 0; k4 < H / 4; ++k4) {
      const float4 va = xa[k4], vb = xb[k4];
      a0 = fmaf(va.x, w[4 * k4 + 0], a0); b0 = fmaf(vb.x, w[4 * k4 + 0], b0);
      a1 = fmaf(va.y, w[4 * k4 + 1], a1); b1 = fmaf(vb.y, w[4 * k4 + 1], b1);
      a2 = fmaf(va.z, w[4 * k4 + 2], a2); b2 = fmaf(vb.z, w[4 * k4 + 2], b2);
      a3 = fmaf(va.w, w[4 * k4 + 3], a3); b3 = fmaf(vb.w, w[4 * k4 + 3], b3);
    }
    sh[(r0 + i) * H + lane] = fmaxf((a0 + a1) + (a2 + a3) + bj, 0.f);
    sh[(r0 + i + 1) * H + lane] = fmaxf((b0 + b1) + (b2 + b3) + bj, 0.f);
  }
}

// pooled[n*128 + colOff + lane] = relu(sh_row@Wp + bp) (guarded global write)
__device__ __forceinline__ void apply_pool_out(
    const float* sh, const float* __restrict__ Wp, const float* __restrict__ bp,
    int lane, int r0, int n0, int N, float* __restrict__ pooled, int colOff)
{
  float w[H];
#pragma unroll
  for (int k = 0; k < H; ++k) w[k] = Wp[k * H + lane];
  const float bj = bp[lane];
  for (int i = 0; i < 16; i += 2) {
    const float4* xa = reinterpret_cast<const float4*>(sh + (r0 + i) * H);
    const float4* xb = reinterpret_cast<const float4*>(sh + (r0 + i + 1) * H);
    float a0 = 0.f, a1 = 0.f, a2 = 0.f, a3 = 0.f;
    float b0 = 0.f, b1 = 0.f, b2 = 0.f, b3 = 0.f;
#pragma unroll
    for (int k4 = 0; k4 < H / 4; ++k4) {
      const float4 va = xa[k4], vb = xb[k4];
      a0 = fmaf(va.x, w[4 * k4 + 0], a0); b0 = fmaf(vb.x, w[4 * k4 + 0], b0);
      a1 = fmaf(va.y, w[4 * k4 + 1], a1); b1 = fmaf(vb.y, w[4 * k4 + 1], b1);
      a2 = fmaf(va.z, w[4 * k4 + 2], a2); b2 = fmaf(vb.z, w[4 * k4 + 2], b2);
      a3 = fmaf(va.w, w[4 * k4 + 3], a3); b3 = fmaf(vb.w, w[4 * k4 + 3], b3);
    }
    const int na = n0 + r0 + i;
    if (na < N)
      pooled[(size_t)na * 128 + colOff + lane] =
          fmaxf((a0 + a1) + (a2 + a3) + bj, 0.f);
    if (na + 1 < N)
      pooled[(size_t)(na + 1) * 128 + colOff + lane] =
          fmaxf((b0 + b1) + (b2 + b3) + bj, 0.f);
  }
}

// ===========================================================================
// emb_pool: x -> h (optional global write) -> pooled_l1 | pooled_l2 (interleaved)
// ===========================================================================
template<int K, bool WRITEH>
__global__ __launch_bounds__(256) void emb_pool_k(
    const float* __restrict__ X, const float* __restrict__ We,
    const float* __restrict__ be,
    const float* __restrict__ Wp1, const float* __restrict__ bp1,
    const float* __restrict__ Wp2, const float* __restrict__ bp2,
    float* __restrict__ h_out, float* __restrict__ pooled, int N)
{
  __shared__ __align__(16) float sxe[TR * K];
  __shared__ __align__(16) float sh[TR * H];
  const int n0 = blockIdx.x * TR;
  {
    const long base = (long)n0 * K, lim = (long)N * K;
    for (int i = threadIdx.x; i < TR * K; i += 256)
      sxe[i] = (base + i < lim) ? X[base + i] : 0.f;
  }
  __syncthreads();
  const int lane = threadIdx.x & 63;
  const int r0 = (threadIdx.x >> 6) * 16;
  {  // embed
    float w[K];
#pragma unroll
    for (int k = 0; k < K; ++k) w[k] = We[k * H + lane];
    const float bj = be[lane];
    for (int i = 0; i < 16; i += 2) {
      const float* xa = sxe + (r0 + i) * K;
      const float* xb = sxe + (r0 + i + 1) * K;
      float a = 0.f, b = 0.f;
#pragma unroll
      for (int k = 0; k < K; ++k) { a = fmaf(xa[k], w[k], a); b = fmaf(xb[k], w[k], b); }
      a = fmaxf(a + bj, 0.f);
      b = fmaxf(b + bj, 0.f);
      sh[(r0 + i) * H + lane] = a;
      sh[(r0 + i + 1) * H + lane] = b;
      if constexpr (WRITEH) {
        const int na = n0 + r0 + i;
        if (na < N) h_out[(size_t)na * H + lane] = a;
        if (na + 1 < N) h_out[(size_t)(na + 1) * H + lane] = b;
      }
    }
  }
  __syncthreads();
  apply_pool_out(sh, Wp1, bp1, lane, r0, n0, N, pooled, 0);
  __syncthreads();
  apply_pool_out(sh, Wp2, bp2, lane, r0, n0, N, pooled, 64);
}

// ===========================================================================
// con_update: con-embed -> l1f update -> l2f update -> l1b pooled | l2b pooled
// h_con never touches global memory.
// ===========================================================================
__global__ __launch_bounds__(256) void con_update_k(
    const float* __restrict__ con_x, const float* __restrict__ We,
    const float* __restrict__ be,
    const float* __restrict__ Ws1, const float* __restrict__ Wn1, const float* __restrict__ b1,
    const float* __restrict__ Ws2, const float* __restrict__ Wn2, const float* __restrict__ b2,
    const float* __restrict__ Wp1, const float* __restrict__ bp1,
    const float* __restrict__ Wp2, const float* __restrict__ bp2,
    const float* __restrict__ agg1, const float* __restrict__ agg2,
    float* __restrict__ pooledB, int N)
{
  __shared__ __align__(16) float sh[TR * H];
  __shared__ __align__(16) float sa1[TR * H];
  __shared__ __align__(16) float sa2[TR * H];
  __shared__ __align__(16) float sxe[TR * 4];
  const int n0 = blockIdx.x * TR;
  {
    const float4* X4 = reinterpret_cast<const float4*>(con_x);  // K=4 => 1 float4/row
    float4* S4 = reinterpret_cast<float4*>(sxe);
    for (int i = threadIdx.x; i < TR; i += 256)
      S4[i] = (n0 + i < N) ? X4[n0 + i] : make_float4(0.f, 0.f, 0.f, 0.f);
  }
  stage_tile(agg1, sa1, n0, N, threadIdx.x);
  stage_tile(agg2, sa2, n0, N, threadIdx.x);
  __syncthreads();
  const int lane = threadIdx.x & 63;
  const int r0 = (threadIdx.x >> 6) * 16;
  {  // embed con (K=4)
    float w[4];
#pragma unroll
    for (int k = 0; k < 4; ++k) w[k] = We[k * H + lane];
    const float bj = be[lane];
    for (int i = 0; i < 16; ++i) {
      const float* x = sxe + (r0 + i) * 4;
      float a = 0.f;
#pragma unroll
      for (int k = 0; k < 4; ++k) a = fmaf(x[k], w[k], a);
      sh[(r0 + i) * H + lane] = fmaxf(a + bj, 0.f);
    }
  }
  __syncthreads();
  apply_layer_inplace(sh, sa1, Ws1, Wn1, b1, lane, r0, 2.f);  // l1f (v2c+s2c share)
  __syncthreads();
  apply_layer_inplace(sh, sa2, Ws2, Wn2, b2, lane, r0, 2.f);  // l2f
  __syncthreads();
  apply_pool_out(sh, Wp1, bp1, lane, r0, n0, N, pooledB, 0);   // l1b pooled
  __syncthreads();
  apply_pool_out(sh, Wp2, bp2, lane, r0, n0, N, pooledB, 64);  // l2b pooled
}

// ===========================================================================
// var_update_mlp: l1b update -> l2b update -> MLP(z@W_hid twice) -> head
// Writes ONLY d_out (h_var final is otherwise dead; soc bwd is dead code).
// ===========================================================================
__global__ __launch_bounds__(256) void var_update_mlp_k(
    const float* __restrict__ hv,
    const float* __restrict__ Ws1, const float* __restrict__ Wn1, const float* __restrict__ b1,
    const float* __restrict__ Ws2, const float* __restrict__ Wn2, const float* __restrict__ b2,
    const float* __restrict__ Wh, const float* __restrict__ bh,
    const float* __restrict__ Wo, const float* __restrict__ bo,
    const float* __restrict__ agg1, const float* __restrict__ agg2,
    float* __restrict__ out, int N)
{
  __shared__ __align__(16) float sh[TR * H];
  __shared__ __align__(16) float sa1[TR * H];
  __shared__ __align__(16) float sa2[TR * H];
  const int n0 = blockIdx.x * TR;
  stage_tile(hv, sh, n0, N, threadIdx.x);
  stage_tile(agg1, sa1, n0, N, threadIdx.x);
  stage_tile(agg2, sa2, n0, N, threadIdx.x);
  __syncthreads();
  const int lane = threadIdx.x & 63;
  const int r0 = (threadIdx.x >> 6) * 16;
  apply_layer_inplace(sh, sa1, Ws1, Wn1, b1, lane, r0, 1.f);  // l1b (c2v)
  __syncthreads();
  apply_layer_inplace(sh, sa2, Ws2, Wn2, b2, lane, r0, 1.f);  // l2b
  __syncthreads();
  apply_lin_inplace(sh, Wh, bh, lane, r0);                    // z1
  __syncthreads();
  {  // z2 + head
    float w[H];
#pragma unroll
    for (int k = 0; k < H; ++k) w[k] = Wh[k * H + lane];
    const float bhl = bh[lane];
    const float wo = Wo[lane];
    const float bol = bo[0];
    for (int i = 0; i < 16; ++i) {
      const int n = n0 + r0 + i;
      const float4* x4 = reinterpret_cast<const float4*>(sh + (r0 + i) * H);
      float a0 = 0.f, a1 = 0.f, a2 = 0.f, a3 = 0.f;
#pragma unroll
      for (int k4 = 0; k4 < H / 4; ++k4) {
        const float4 v = x4[k4];
        a0 = fmaf(v.x, w[4 * k4 + 0], a0);
        a1 = fmaf(v.y, w[4 * k4 + 1], a1);
        a2 = fmaf(v.z, w[4 * k4 + 2], a2);
        a3 = fmaf(v.w, w[4 * k4 + 3], a3);
      }
      const float z2 = fmaxf((a0 + a1) + (a2 + a3) + bhl, 0.f);
      float v = z2 * wo;
#pragma unroll
      for (int off = 32; off; off >>= 1) v += __shfl_down(v, off);
      if (lane == 0 && n < N) out[n] = v + bol;
    }
  }
}

// ===========================================================================
// Bucketed CSR build. Dual variant reads the edge list ONCE for both keys.
// ===========================================================================
__global__ __launch_bounds__(256) void bhist2_k(
    const int* __restrict__ kD, const int* __restrict__ kS,
    int* __restrict__ bcntD, int* __restrict__ bcntS, int E, int nbD, int nbS)
{
  __shared__ int hD[NBMAX], hS[NBMAX];
  for (int i = threadIdx.x; i < NBMAX; i += 256) { hD[i] = 0; hS[i] = 0; }
  __syncthreads();
  const int base = blockIdx.x * EPB;
  for (int i = threadIdx.x; i < EPB; i += 256) {
    const int e = base + i;
    if (e < E) {
      atomicAdd(&hD[kD[e] >> BSH], 1);
      atomicAdd(&hS[kS[e] >> BSH], 1);
    }
  }
  __syncthreads();
  for (int i = threadIdx.x; i < nbD; i += 256) if (hD[i]) atomicAdd(&bcntD[i], hD[i]);
  for (int i = threadIdx.x; i < nbS; i += 256) if (hS[i]) atomicAdd(&bcntS[i], hS[i]);
}

__global__ __launch_bounds__(256) void bhist_k(const int* __restrict__ key,
                                               int* __restrict__ bcnt, int E, int nb) {
  __shared__ int h[NBMAX];
  for (int i = threadIdx.x; i < NBMAX; i += 256) h[i] = 0;
  __syncthreads();
  const int base = blockIdx.x * EPB;
  for (int i = threadIdx.x; i < EPB; i += 256) {
    const int e = base + i;
    if (e < E) atomicAdd(&h[key[e] >> BSH], 1);
  }
  __syncthreads();
  for (int i = threadIdx.x; i < nb; i += 256)
    if (h[i]) atomicAdd(&bcnt[i], h[i]);
}

__device__ __forceinline__ void scan_dev(const int* __restrict__ cnt,
                                         int* __restrict__ cur,
                                         int* __restrict__ sbase, int nb, int* s) {
  const int t = threadIdx.x;
  const int v = (t < nb) ? cnt[t] : 0;
  s[t] = v;
  __syncthreads();
  for (int off = 1; off < 1024; off <<= 1) {
    int x = (t >= off) ? s[t - off] : 0;
    __syncthreads();
    s[t] += x;
    __syncthreads();
  }
  if (t < nb) {
    const int ex = s[t] - v;
    cur[t] = ex;
    sbase[t] = ex;
    if (t == nb - 1) sbase[nb] = s[t];
  }
  __syncthreads();
}

__global__ __launch_bounds__(1024) void bscan2_k(
    const int* __restrict__ cD, int* __restrict__ curD, int* __restrict__ sbD, int nbD,
    const int* __restrict__ cS, int* __restrict__ curS, int* __restrict__ sbS, int nbS) {
  __shared__ int s[1024];
  scan_dev(cD, curD, sbD, nbD, s);
  scan_dev(cS, curS, sbS, nbS, s);
}

__global__ __launch_bounds__(1024) void bscan1_k(
    const int* __restrict__ c, int* __restrict__ cur, int* __restrict__ sb, int nb) {
  __shared__ int s[1024];
  scan_dev(c, cur, sb, nb, s);
}

__global__ __launch_bounds__(256) void bscatter2_k(
    const int* __restrict__ kD, const int* __restrict__ kS,
    int* __restrict__ bcurD, int* __restrict__ bcurS,
    int2* __restrict__ sortedD, int2* __restrict__ sortedS, int E, int nbD, int nbS)
{
  __shared__ int hD[NBMAX], gbD[NBMAX], hS[NBMAX], gbS[NBMAX];
  __shared__ unsigned short lrD[EPB], lrS[EPB];
  for (int i = threadIdx.x; i < NBMAX; i += 256) { hD[i] = 0; hS[i] = 0; }
  __syncthreads();
  const int base = blockIdx.x * EPB;
  for (int i = threadIdx.x; i < EPB; i += 256) {
    const int e = base + i;
    if (e < E) {
      lrD[i] = (unsigned short)atomicAdd(&hD[kD[e] >> BSH], 1);
      lrS[i] = (unsigned short)atomicAdd(&hS[kS[e] >> BSH], 1);
    }
  }
  __syncthreads();
  for (int i = threadIdx.x; i < nbD; i += 256) if (hD[i]) gbD[i] = atomicAdd(&bcurD[i], hD[i]);
  for (int i = threadIdx.x; i < nbS; i += 256) if (hS[i]) gbS[i] = atomicAdd(&bcurS[i], hS[i]);
  __syncthreads();
  for (int i = threadIdx.x; i < EPB; i += 256) {
    const int e = base + i;
    if (e < E) {
      const int d = kD[e], s = kS[e];
      sortedD[gbD[d >> BSH] + lrD[i]] = make_int2(d, s);
      sortedS[gbS[s >> BSH] + lrS[i]] = make_int2(s, d);
    }
  }
}

__global__ __launch_bounds__(256) void bscatter_k(
    const int* __restrict__ key, const int* __restrict__ payload,
    int* __restrict__ bcur, int2* __restrict__ sorted, int E, int nb) {
  __shared__ int h[NBMAX];
  __shared__ int gb[NBMAX];
  __shared__ unsigned short lr[EPB];
  for (int i = threadIdx.x; i < NBMAX; i += 256) h[i] = 0;
  __syncthreads();
  const int base = blockIdx.x * EPB;
  for (int i = threadIdx.x; i < EPB; i += 256) {
    const int e = base + i;
    if (e < E) lr[i] = (unsigned short)atomicAdd(&h[key[e] >> BSH], 1);
  }
  __syncthreads();
  for (int i = threadIdx.x; i < nb; i += 256)
    if (h[i]) gb[i] = atomicAdd(&bcur[i], h[i]);
  __syncthreads();
  for (int i = threadIdx.x; i < EPB; i += 256) {
    const int e = base + i;
    if (e < E) {
      const int k = key[e];
      sorted[gb[k >> BSH] + lr[i]] = make_int2(k, payload[e]);
    }
  }
}

// one block per bucket: LDS degree histogram + scan -> rowptr; LDS-cursor fill
__global__ __launch_bounds__(256) void bfinish_k(
    const int2* __restrict__ sorted, const int* __restrict__ sbase,
    int* __restrict__ rp, int* __restrict__ ei, int Nn) {
  __shared__ int cnt[128];
  __shared__ int scn[128];
  const int b = blockIdx.x;
  const int node0 = b << BSH;
  const int e0 = sbase[b], e1 = sbase[b + 1];
  const int t = threadIdx.x;
  if (t < 128) cnt[t] = 0;
  __syncthreads();
  for (int e = e0 + t; e < e1; e += 256)
    atomicAdd(&cnt[sorted[e].x - node0], 1);
  __syncthreads();
  if (t < 128) scn[t] = cnt[t];
  __syncthreads();
#pragma unroll
  for (int off = 1; off < 128; off <<= 1) {
    int v = (t < 128 && t >= off) ? scn[t - off] : 0;
    __syncthreads();
    if (t < 128) scn[t] += v;
    __syncthreads();
  }
  const int nInB = (Nn - node0 < 128) ? (Nn - node0) : 128;
  int myexcl = 0;
  if (t < 128) myexcl = scn[t] - cnt[t];
  if (t < nInB) rp[node0 + t] = e0 + myexcl;
  if (b == (int)gridDim.x - 1 && t == 0) rp[Nn] = e1;
  __syncthreads();
  if (t < 128) cnt[t] = myexcl;
  __syncthreads();
  for (int e = e0 + t; e < e1; e += 256) {
    const int2 kp = sorted[e];
    const int p = atomicAdd(&cnt[kp.x - node0], 1);
    ei[e0 + p] = kp.y;
  }
}

// ===========================================================================
// Gathers over interleaved 512B rows [pooled_l1 | pooled_l2].
// 32 lanes per row; 16 edges (8KB) in flight per wave; wave per dst node.
// ===========================================================================
__device__ __forceinline__ float4 fmax4(float4 a, float4 b) {
  return make_float4(fmaxf(a.x, b.x), fmaxf(a.y, b.y),
                     fmaxf(a.z, b.z), fmaxf(a.w, b.w));
}

__device__ __forceinline__ float4 gmax2_csr(const float4* __restrict__ t4,
                                            const int* __restrict__ rp,
                                            const int* __restrict__ ei,
                                            int n, int g, int sub) {
  const int p0 = rp[n], p1 = rp[n + 1];
  const float4 z = make_float4(0.f, 0.f, 0.f, 0.f);
  float4 m0 = z, m1 = z, m2 = z, m3 = z, m4 = z, m5 = z, m6 = z, m7 = z;
  if (p1 > p0) {
    const int last = p1 - 1;
    for (int p = p0; p < p1; p += 16) {
      int e0 = p + 0 + g;  e0 = e0 <= last ? e0 : last;
      int e1 = p + 2 + g;  e1 = e1 <= last ? e1 : last;
      int e2 = p + 4 + g;  e2 = e2 <= last ? e2 : last;
      int e3 = p + 6 + g;  e3 = e3 <= last ? e3 : last;
      int e4 = p + 8 + g;  e4 = e4 <= last ? e4 : last;
      int e5 = p + 10 + g; e5 = e5 <= last ? e5 : last;
      int e6 = p + 12 + g; e6 = e6 <= last ? e6 : last;
      int e7 = p + 14 + g; e7 = e7 <= last ? e7 : last;
      const int s0 = ei[e0], s1 = ei[e1], s2 = ei[e2], s3 = ei[e3];
      const int s4 = ei[e4], s5 = ei[e5], s6 = ei[e6], s7 = ei[e7];
      m0 = fmax4(m0, t4[(size_t)s0 * 32 + sub]);
      m1 = fmax4(m1, t4[(size_t)s1 * 32 + sub]);
      m2 = fmax4(m2, t4[(size_t)s2 * 32 + sub]);
      m3 = fmax4(m3, t4[(size_t)s3 * 32 + sub]);
      m4 = fmax4(m4, t4[(size_t)s4 * 32 + sub]);
      m5 = fmax4(m5, t4[(size_t)s5 * 32 + sub]);
      m6 = fmax4(m6, t4[(size_t)s6 * 32 + sub]);
      m7 = fmax4(m7, t4[(size_t)s7 * 32 + sub]);
    }
  }
  float4 m = fmax4(fmax4(fmax4(m0, m1), fmax4(m2, m3)),
                   fmax4(fmax4(m4, m5), fmax4(m6, m7)));
  m.x = fmaxf(m.x, __shfl_xor(m.x, 32));
  m.y = fmaxf(m.y, __shfl_xor(m.y, 32));
  m.z = fmaxf(m.z, __shfl_xor(m.z, 32));
  m.w = fmaxf(m.w, __shfl_xor(m.w, 32));
  return m;
}

// fwd: agg{1,2}[n] = maxVar + maxSoc (both relations, summed per HeteroConv)
__global__ __launch_bounds__(256) void gather2f_k(
    const float4* __restrict__ t4,
    const int* __restrict__ rpCv, const int* __restrict__ eiCv,
    const int* __restrict__ rpCs, const int* __restrict__ eiCs,
    float4* __restrict__ agg1, float4* __restrict__ agg2, int N)
{
  const int lane = threadIdx.x & 63;
  const int g = lane >> 5, sub = lane & 31;
  const int n = __builtin_amdgcn_readfirstlane(blockIdx.x * 4 + (threadIdx.x >> 6));
  if (n >= N) return;
  const float4 a = gmax2_csr(t4, rpCv, eiCv, n, g, sub);
  const float4 b = gmax2_csr(t4 + (size_t)NV * 32, rpCs, eiCs, n, g, sub);
  const float4 r = make_float4(a.x + b.x, a.y + b.y, a.z + b.z, a.w + b.w);
  if (g == 0) {
    if (sub < 16) agg1[(size_t)n * 16 + sub] = r;
    else          agg2[(size_t)n * 16 + (sub - 16)] = r;
  }
}

// bwd (var only -- soc backward is dead code)
__global__ __launch_bounds__(256) void gatherB_k(
    const float4* __restrict__ t4,
    const int* __restrict__ rp, const int* __restrict__ ei,
    float4* __restrict__ agg1, float4* __restrict__ agg2, int N)
{
  const int lane = threadIdx.x & 63;
  const int g = lane >> 5, sub = lane & 31;
  const int n = __builtin_amdgcn_readfirstlane(blockIdx.x * 4 + (threadIdx.x >> 6));
  if (n >= N) return;
  const float4 m = gmax2_csr(t4, rp, ei, n, g, sub);
  if (g == 0) {
    if (sub < 16) agg1[(size_t)n * 16 + sub] = m;
    else          agg2[(size_t)n * 16 + (sub - 16)] = m;
  }
}

extern "C" void kernel_launch(void* const* d_in, const int* in_sizes, int n_in,
                              void* d_out, int out_size, void* d_ws, size_t ws_size,
                              hipStream_t stream) {
  const float* var_x = (const float*)d_in[0];
  const float* con_x = (const float*)d_in[1];
  const float* soc_x = (const float*)d_in[2];
  const float* W_var = (const float*)d_in[3];
  const float* b_var = (const float*)d_in[4];
  const float* W_con = (const float*)d_in[5];
  const float* b_con = (const float*)d_in[6];
  const float* W_soc = (const float*)d_in[7];
  const float* b_soc = (const float*)d_in[8];
  const float* L[4][5];  // L[0]=l1f, L[1]=l1b, L[2]=l2f, L[3]=l2b; 0=Wp 1=bp 2=Ws 3=Wn 4=b
  for (int l = 0; l < 4; ++l)
    for (int p = 0; p < 5; ++p)
      L[l][p] = (const float*)d_in[9 + l * 5 + p];
  const float* W_hid = (const float*)d_in[29];
  const float* b_hid = (const float*)d_in[30];
  const float* W_out = (const float*)d_in[31];
  const float* b_out = (const float*)d_in[32];
  const int* vc_src = (const int*)d_in[33];
  const int* vc_dst = (const int*)d_in[34];
  const int* sc_src = (const int*)d_in[35];
  const int* sc_dst = (const int*)d_in[36];

  char* ws = (char*)d_ws;
  const size_t SZ_HV = (size_t)NV * H * 4;        // 25.6 MB
  const size_t SZ_PF = (size_t)NVS * 128 * 4;     // 61.44 MB
  const size_t SZ_AF = 2ull * NC * H * 4;         // 51.2 MB
  const size_t SZ_PB = (size_t)NC * 128 * 4;      // 51.2 MB
  float* h_var   = (float*)ws;
  float* pooledF = (float*)(ws + SZ_HV);
  float* agg1b   = pooledF;                        // alias: pooledF dead after gather2f
  float* agg2b   = pooledF + (size_t)NV * H;
  float* agg1f   = (float*)(ws + SZ_HV + SZ_PF);
  float* agg2f   = agg1f + (size_t)NC * H;
  int2*  sortedD = (int2*)agg1f;                   // alias: dead before gather2f writes
  int2*  sortedS = (int2*)((char*)agg1f + (size_t)EVC * 8);
  float* pooledB = (float*)(ws + SZ_HV + SZ_PF + SZ_AF);
  int* csr = (int*)(ws + SZ_HV + SZ_PF + SZ_AF + SZ_PB);
  int* rpCv = csr;
  int* eiCv = rpCv + (NC + 1);
  int* rpCs = eiCv + EVC;
  int* eiCs = rpCs + (NC + 1);
  int* rpV  = eiCs + ESC;
  int* eiV  = rpV + (NV + 1);
  int* aux  = eiV + EVC;
  int* bcntD = aux;
  int* bcntS = aux + 1024;
  int* bcntC = aux + 2048;
  int* bcurD = aux + 3072;
  int* bcurS = aux + 4096;
  int* bcurC = aux + 5120;
  int* sbD   = aux + 6144;   // 1025 each
  int* sbS   = sbD + 1056;
  int* sbC   = sbS + 1056;

  const int nbC = (NC + 127) >> BSH;   // 782
  const int nbV = (NV + 127) >> BSH;   // 782
  auto grid_l = [](int n) { return dim3((unsigned)((n + TR - 1) / TR)); };
  auto grid_w = [](int n) { return dim3((unsigned)((n + 3) / 4)); };
  auto grid_b = [](int e) { return dim3((unsigned)((e + EPB - 1) / EPB)); };
  const dim3 B(256);

  hipMemsetAsync(aux, 0, 3072 * sizeof(int), stream);  // the 3 bcnt arrays

  // ---- CSR builds: vc dual (dst & src keyed from ONE edge-list read) ------
  bhist2_k<<<grid_b(EVC), B, 0, stream>>>(vc_dst, vc_src, bcntD, bcntS, EVC, nbC, nbV);
  bscan2_k<<<dim3(1), dim3(1024), 0, stream>>>(bcntD, bcurD, sbD, nbC, bcntS, bcurS, sbS, nbV);
  bscatter2_k<<<grid_b(EVC), B, 0, stream>>>(vc_dst, vc_src, bcurD, bcurS, sortedD, sortedS, EVC, nbC, nbV);
  bfinish_k<<<dim3((unsigned)nbC), B, 0, stream>>>(sortedD, sbD, rpCv, eiCv, NC);
  bfinish_k<<<dim3((unsigned)nbV), B, 0, stream>>>(sortedS, sbS, rpV, eiV, NV);
  // sc: dst-keyed only (sc_src CSR was dead code)
  bhist_k<<<grid_b(ESC), B, 0, stream>>>(sc_dst, bcntC, ESC, nbC);
  bscan1_k<<<dim3(1), dim3(1024), 0, stream>>>(bcntC, bcurC, sbC, nbC);
  bscatter_k<<<grid_b(ESC), B, 0, stream>>>(sc_dst, sc_src, bcurC, sortedD, ESC, nbC);
  bfinish_k<<<dim3((unsigned)nbC), B, 0, stream>>>(sortedD, sbC, rpCs, eiCs, NC);

  // ---- embeddings + both fwd pooled tables (interleaved l1f|l2f) ----------
  emb_pool_k<7, true><<<grid_l(NV), B, 0, stream>>>(
      var_x, W_var, b_var, L[0][0], L[0][1], L[2][0], L[2][1], h_var, pooledF, NV);
  emb_pool_k<6, false><<<grid_l(NSOC), B, 0, stream>>>(
      soc_x, W_soc, b_soc, L[0][0], L[0][1], L[2][0], L[2][1], nullptr,
      pooledF + (size_t)NV * 128, NSOC);

  // ---- fwd gather (both layers at once) -----------------------------------
  gather2f_k<<<grid_w(NC), B, 0, stream>>>(
      (const float4*)pooledF, rpCv, eiCv, rpCs, eiCs,
      (float4*)agg1f, (float4*)agg2f, NC);

  // ---- con: embed + 2 fwd updates + both bwd pooled tables ----------------
  con_update_k<<<grid_l(NC), B, 0, stream>>>(
      con_x, W_con, b_con,
      L[0][2], L[0][3], L[0][4], L[2][2], L[2][3], L[2][4],
      L[1][0], L[1][1], L[3][0], L[3][1],
      agg1f, agg2f, pooledB, NC);

  // ---- bwd gather (var only) ----------------------------------------------
  gatherB_k<<<grid_w(NV), B, 0, stream>>>(
      (const float4*)pooledB, rpV, eiV, (float4*)agg1b, (float4*)agg2b, NV);

  // ---- var: 2 bwd updates + MLP + head -> d_out ---------------------------
  var_update_mlp_k<<<grid_l(NV), B, 0, stream>>>(
      h_var,
      L[1][2], L[1][3], L[1][4], L[3][2], L[3][3], L[3][4],
      W_hid, b_hid, W_out, b_out,
      agg1b, agg2b, (float*)d_out, NV);
}

// Round 9
// 753.197 us; speedup vs baseline: 1.3362x; 1.3362x over previous
//
#include <hip/hip_runtime.h>

#define NV 100000
#define NC 100000
#define NSOC 20000
#define NVS (NV + NSOC)
#define EVC 2000000
#define ESC 300000
#define H 64

constexpr int BSH = 7;       // 128 nodes per bucket
constexpr int NBMAX = 1024;  // max buckets
constexpr int EPB = 8192;    // edges per block in bucket passes
constexpr int TR = 64;       // rows per block in GEMM kernels

// ---------------------------------------------------------------------------
// LDS-tiled fused GEMM (r7-proven; 2-row ILP; in-place safe via LDS staging).
//   out[n][j] = act( s1*(dot(X1[n],W1[:,j]) + bias[j]) + [NSEC] dot(X2[n],W2[:,j]) )
// LDS 16/32KB -> 5-8 blocks/CU. Do NOT fuse more phases (r8: 50KB LDS, 10%
// occupancy, 266us). Do NOT widen to 4-row ILP (r5: 256 VGPR spill).
// ---------------------------------------------------------------------------
template<int K1, int NSEC, bool RELU, int TRr>
__global__ __launch_bounds__(256) void gemm_lds(
    const float* X1, const float* __restrict__ W1,
    const float* __restrict__ X2, const float* __restrict__ W2,
    const float* __restrict__ bias, float* out,
    int N, float s1)
{
  __shared__ __align__(16) float sx1[TRr * K1];
  __shared__ __align__(16) float sx2[NSEC ? TRr * H : 4];

  const int n0 = blockIdx.x * TRr;

  if constexpr ((K1 & 3) == 0) {
    const float4* X4 = reinterpret_cast<const float4*>(X1);
    float4* S4 = reinterpret_cast<float4*>(sx1);
    const long base4 = (long)n0 * K1 / 4;
    const long lim4 = (long)N * K1 / 4;
    for (int i = threadIdx.x; i < TRr * K1 / 4; i += 256)
      S4[i] = (base4 + i < lim4) ? X4[base4 + i] : make_float4(0.f, 0.f, 0.f, 0.f);
  } else {
    const long base = (long)n0 * K1;
    const long lim = (long)N * K1;
    for (int i = threadIdx.x; i < TRr * K1; i += 256)
      sx1[i] = (base + i < lim) ? X1[base + i] : 0.f;
  }
  if constexpr (NSEC) {
    const float4* X4 = reinterpret_cast<const float4*>(X2);
    float4* S4 = reinterpret_cast<float4*>(sx2);
    const long base4 = (long)n0 * H / 4;
    const long lim4 = (long)N * H / 4;
    for (int i = threadIdx.x; i < TRr * H / 4; i += 256)
      S4[i] = (base4 + i < lim4) ? X4[base4 + i] : make_float4(0.f, 0.f, 0.f, 0.f);
  }
  __syncthreads();

  const int lane = threadIdx.x & 63;
  const int wv = threadIdx.x >> 6;

  float w1[K1];
#pragma unroll
  for (int k = 0; k < K1; ++k) w1[k] = W1[k * H + lane];
  float w2[NSEC ? H : 1];
  if constexpr (NSEC) {
#pragma unroll
    for (int k = 0; k < H; ++k) w2[k] = W2[k * H + lane];
  }
  const float bj = bias[lane];

  constexpr int RPW = TRr / 4;
  const int r0 = wv * RPW;

  if constexpr (K1 == H) {
    for (int i = 0; i < RPW; i += 2) {
      const int na = n0 + r0 + i;
      if (na >= N) break;
      const bool wb = (na + 1) < N;

      const float4* xa = reinterpret_cast<const float4*>(sx1 + (r0 + i) * H);
      const float4* xb = reinterpret_cast<const float4*>(sx1 + (r0 + i + 1) * H);
      float a0 = 0.f, a1 = 0.f, a2 = 0.f, a3 = 0.f;
      float b0 = 0.f, b1 = 0.f, b2 = 0.f, b3 = 0.f;
#pragma unroll
      for (int k4 = 0; k4 < H / 4; ++k4) {
        const float4 va = xa[k4];
        const float4 vb = xb[k4];
        a0 = fmaf(va.x, w1[4 * k4 + 0], a0);
        b0 = fmaf(vb.x, w1[4 * k4 + 0], b0);
        a1 = fmaf(va.y, w1[4 * k4 + 1], a1);
        b1 = fmaf(vb.y, w1[4 * k4 + 1], b1);
        a2 = fmaf(va.z, w1[4 * k4 + 2], a2);
        b2 = fmaf(vb.z, w1[4 * k4 + 2], b2);
        a3 = fmaf(va.w, w1[4 * k4 + 3], a3);
        b3 = fmaf(vb.w, w1[4 * k4 + 3], b3);
      }
      float accA = s1 * (((a0 + a1) + (a2 + a3)) + bj);
      float accB = s1 * (((b0 + b1) + (b2 + b3)) + bj);

      if constexpr (NSEC) {
        const float4* ya = reinterpret_cast<const float4*>(sx2 + (r0 + i) * H);
        const float4* yb = reinterpret_cast<const float4*>(sx2 + (r0 + i + 1) * H);
        a0 = 0.f; a1 = 0.f; a2 = 0.f; a3 = 0.f;
        b0 = 0.f; b1 = 0.f; b2 = 0.f; b3 = 0.f;
#pragma unroll
        for (int k4 = 0; k4 < H / 4; ++k4) {
          const float4 va = ya[k4];
          const float4 vb = yb[k4];
          a0 = fmaf(va.x, w2[4 * k4 + 0], a0);
          b0 = fmaf(vb.x, w2[4 * k4 + 0], b0);
          a1 = fmaf(va.y, w2[4 * k4 + 1], a1);
          b1 = fmaf(vb.y, w2[4 * k4 + 1], b1);
          a2 = fmaf(va.z, w2[4 * k4 + 2], a2);
          b2 = fmaf(vb.z, w2[4 * k4 + 2], b2);
          a3 = fmaf(va.w, w2[4 * k4 + 3], a3);
          b3 = fmaf(vb.w, w2[4 * k4 + 3], b3);
        }
        accA += (a0 + a1) + (a2 + a3);
        accB += (b0 + b1) + (b2 + b3);
      }

      if constexpr (RELU) { accA = fmaxf(accA, 0.f); accB = fmaxf(accB, 0.f); }
      out[(size_t)na * H + lane] = accA;
      if (wb) out[(size_t)(na + 1) * H + lane] = accB;
    }
  } else {
    for (int i = 0; i < RPW; i += 2) {
      const int na = n0 + r0 + i;
      if (na >= N) break;
      const bool wb = (na + 1) < N;
      const float* xa = sx1 + (r0 + i) * K1;
      const float* xb = sx1 + (r0 + i + 1) * K1;
      float accA = 0.f, accB = 0.f;
#pragma unroll
      for (int k = 0; k < K1; ++k) {
        accA = fmaf(xa[k], w1[k], accA);
        accB = fmaf(xb[k], w1[k], accB);
      }
      accA = s1 * (accA + bj);
      accB = s1 * (accB + bj);
      if constexpr (RELU) { accA = fmaxf(accA, 0.f); accB = fmaxf(accB, 0.f); }
      out[(size_t)na * H + lane] = accA;
      if (wb) out[(size_t)(na + 1) * H + lane] = accB;
    }
  }
}

// ---------------------------------------------------------------------------
// Dual-output GEMM (r7-proven): one staged X tile, two weight sets,
// interleaved 128-wide output rows [colA | colB].
// ---------------------------------------------------------------------------
template<int TRr>
__global__ __launch_bounds__(256) void dualgemm_k(
    const float* __restrict__ X, const float* __restrict__ Wa,
    const float* __restrict__ ba, const float* __restrict__ Wb,
    const float* __restrict__ bb, float* __restrict__ out, int N)
{
  __shared__ __align__(16) float sx[TRr * H];
  const int n0 = blockIdx.x * TRr;
  {
    const float4* X4 = reinterpret_cast<const float4*>(X);
    float4* S4 = reinterpret_cast<float4*>(sx);
    const long base4 = (long)n0 * (H / 4);
    const long lim4 = (long)N * (H / 4);
    for (int i = threadIdx.x; i < TRr * H / 4; i += 256)
      S4[i] = (base4 + i < lim4) ? X4[base4 + i] : make_float4(0.f, 0.f, 0.f, 0.f);
  }
  __syncthreads();

  const int lane = threadIdx.x & 63;
  const int wv = threadIdx.x >> 6;
  float wA[H], wB[H];
#pragma unroll
  for (int k = 0; k < H; ++k) { wA[k] = Wa[k * H + lane]; wB[k] = Wb[k * H + lane]; }
  const float bja = ba[lane];
  const float bjb = bb[lane];

  constexpr int RPW = TRr / 4;
  const int r0 = wv * RPW;
  for (int i = 0; i < RPW; i += 2) {
    const int na = n0 + r0 + i;
    if (na >= N) break;
    const bool hasB = (na + 1) < N;

    const float4* xa = reinterpret_cast<const float4*>(sx + (r0 + i) * H);
    const float4* xb = reinterpret_cast<const float4*>(sx + (r0 + i + 1) * H);
    float pa0 = 0.f, pa1 = 0.f, pa2 = 0.f, pa3 = 0.f;
    float pb0 = 0.f, pb1 = 0.f, pb2 = 0.f, pb3 = 0.f;
    float qa0 = 0.f, qa1 = 0.f, qa2 = 0.f, qa3 = 0.f;
    float qb0 = 0.f, qb1 = 0.f, qb2 = 0.f, qb3 = 0.f;
#pragma unroll
    for (int k4 = 0; k4 < H / 4; ++k4) {
      const float4 va = xa[k4];
      const float4 vb = xb[k4];
      pa0 = fmaf(va.x, wA[4 * k4 + 0], pa0);
      pb0 = fmaf(vb.x, wA[4 * k4 + 0], pb0);
      qa0 = fmaf(va.x, wB[4 * k4 + 0], qa0);
      qb0 = fmaf(vb.x, wB[4 * k4 + 0], qb0);
      pa1 = fmaf(va.y, wA[4 * k4 + 1], pa1);
      pb1 = fmaf(vb.y, wA[4 * k4 + 1], pb1);
      qa1 = fmaf(va.y, wB[4 * k4 + 1], qa1);
      qb1 = fmaf(vb.y, wB[4 * k4 + 1], qb1);
      pa2 = fmaf(va.z, wA[4 * k4 + 2], pa2);
      pb2 = fmaf(vb.z, wA[4 * k4 + 2], pb2);
      qa2 = fmaf(va.z, wB[4 * k4 + 2], qa2);
      qb2 = fmaf(vb.z, wB[4 * k4 + 2], qb2);
      pa3 = fmaf(va.w, wA[4 * k4 + 3], pa3);
      pb3 = fmaf(vb.w, wA[4 * k4 + 3], pb3);
      qa3 = fmaf(va.w, wB[4 * k4 + 3], qa3);
      qb3 = fmaf(vb.w, wB[4 * k4 + 3], qb3);
    }
    out[(size_t)na * 128 + lane] = fmaxf((pa0 + pa1) + (pa2 + pa3) + bja, 0.f);
    out[(size_t)na * 128 + 64 + lane] = fmaxf((qa0 + qa1) + (qa2 + qa3) + bjb, 0.f);
    if (hasB) {
      out[(size_t)(na + 1) * 128 + lane] = fmaxf((pb0 + pb1) + (pb2 + pb3) + bja, 0.f);
      out[(size_t)(na + 1) * 128 + 64 + lane] = fmaxf((qb0 + qb1) + (qb2 + qb3) + bjb, 0.f);
    }
  }
}

// ---------------------------------------------------------------------------
// Fused output MLP (r7-proven): z1=relu(x@W+b); z2=relu(z1@W+b); out=z2@Wout+bo.
// ---------------------------------------------------------------------------
template<int TRr>
__global__ __launch_bounds__(256) void mlp_k(
    const float* __restrict__ X, const float* __restrict__ W,
    const float* __restrict__ bh, const float* __restrict__ Wout,
    const float* __restrict__ bo, float* __restrict__ out, int N)
{
  __shared__ __align__(16) float sx[TRr * H];
  __shared__ __align__(16) float sz[4][H];

  const int n0 = blockIdx.x * TRr;
  {
    const float4* X4 = reinterpret_cast<const float4*>(X);
    float4* S4 = reinterpret_cast<float4*>(sx);
    const long base4 = (long)n0 * H / 4;
    const long lim4 = (long)N * H / 4;
    for (int i = threadIdx.x; i < TRr * H / 4; i += 256)
      S4[i] = (base4 + i < lim4) ? X4[base4 + i] : make_float4(0.f, 0.f, 0.f, 0.f);
  }
  __syncthreads();

  const int lane = threadIdx.x & 63;
  const int wv = threadIdx.x >> 6;
  float w[H];
#pragma unroll
  for (int k = 0; k < H; ++k) w[k] = W[k * H + lane];
  const float bhl = bh[lane];
  const float wo = Wout[lane];
  const float bol = bo[0];

  constexpr int RPW = TRr / 4;
  const int r0 = wv * RPW;
  for (int i = 0; i < RPW; ++i) {
    const int n = n0 + r0 + i;
    if (n >= N) break;
    const float4* x4 = reinterpret_cast<const float4*>(sx + (r0 + i) * H);
    float a0 = 0.f, a1 = 0.f, a2 = 0.f, a3 = 0.f;
#pragma unroll
    for (int k4 = 0; k4 < H / 4; ++k4) {
      const float4 v = x4[k4];
      a0 = fmaf(v.x, w[4 * k4 + 0], a0);
      a1 = fmaf(v.y, w[4 * k4 + 1], a1);
      a2 = fmaf(v.z, w[4 * k4 + 2], a2);
      a3 = fmaf(v.w, w[4 * k4 + 3], a3);
    }
    const float z1 = fmaxf((a0 + a1) + (a2 + a3) + bhl, 0.f);
    sz[wv][lane] = z1;
    const float4* z4 = reinterpret_cast<const float4*>(sz[wv]);
    a0 = 0.f; a1 = 0.f; a2 = 0.f; a3 = 0.f;
#pragma unroll
    for (int k4 = 0; k4 < H / 4; ++k4) {
      const float4 v = z4[k4];
      a0 = fmaf(v.x, w[4 * k4 + 0], a0);
      a1 = fmaf(v.y, w[4 * k4 + 1], a1);
      a2 = fmaf(v.z, w[4 * k4 + 2], a2);
      a3 = fmaf(v.w, w[4 * k4 + 3], a3);
    }
    const float z2 = fmaxf((a0 + a1) + (a2 + a3) + bhl, 0.f);
    float v = z2 * wo;
#pragma unroll
    for (int off = 32; off; off >>= 1) v += __shfl_down(v, off);
    if (lane == 0) out[n] = v + bol;
  }
}

// ===========================================================================
// Bucketed CSR build (r8). Dual variant reads the vc edge list ONCE.
// ===========================================================================
__global__ __launch_bounds__(256) void bhist2_k(
    const int* __restrict__ kD, const int* __restrict__ kS,
    int* __restrict__ bcntD, int* __restrict__ bcntS, int E, int nbD, int nbS)
{
  __shared__ int hD[NBMAX], hS[NBMAX];
  for (int i = threadIdx.x; i < NBMAX; i += 256) { hD[i] = 0; hS[i] = 0; }
  __syncthreads();
  const int base = blockIdx.x * EPB;
  for (int i = threadIdx.x; i < EPB; i += 256) {
    const int e = base + i;
    if (e < E) {
      atomicAdd(&hD[kD[e] >> BSH], 1);
      atomicAdd(&hS[kS[e] >> BSH], 1);
    }
  }
  __syncthreads();
  for (int i = threadIdx.x; i < nbD; i += 256) if (hD[i]) atomicAdd(&bcntD[i], hD[i]);
  for (int i = threadIdx.x; i < nbS; i += 256) if (hS[i]) atomicAdd(&bcntS[i], hS[i]);
}

__global__ __launch_bounds__(256) void bhist_k(const int* __restrict__ key,
                                               int* __restrict__ bcnt, int E, int nb) {
  __shared__ int h[NBMAX];
  for (int i = threadIdx.x; i < NBMAX; i += 256) h[i] = 0;
  __syncthreads();
  const int base = blockIdx.x * EPB;
  for (int i = threadIdx.x; i < EPB; i += 256) {
    const int e = base + i;
    if (e < E) atomicAdd(&h[key[e] >> BSH], 1);
  }
  __syncthreads();
  for (int i = threadIdx.x; i < nb; i += 256)
    if (h[i]) atomicAdd(&bcnt[i], h[i]);
}

__device__ __forceinline__ void scan_dev(const int* __restrict__ cnt,
                                         int* __restrict__ cur,
                                         int* __restrict__ sbase, int nb, int* s) {
  const int t = threadIdx.x;
  const int v = (t < nb) ? cnt[t] : 0;
  s[t] = v;
  __syncthreads();
  for (int off = 1; off < 1024; off <<= 1) {
    int x = (t >= off) ? s[t - off] : 0;
    __syncthreads();
    s[t] += x;
    __syncthreads();
  }
  if (t < nb) {
    const int ex = s[t] - v;
    cur[t] = ex;
    sbase[t] = ex;
    if (t == nb - 1) sbase[nb] = s[t];
  }
  __syncthreads();
}

__global__ __launch_bounds__(1024) void bscan2_k(
    const int* __restrict__ cD, int* __restrict__ curD, int* __restrict__ sbD, int nbD,
    const int* __restrict__ cS, int* __restrict__ curS, int* __restrict__ sbS, int nbS) {
  __shared__ int s[1024];
  scan_dev(cD, curD, sbD, nbD, s);
  scan_dev(cS, curS, sbS, nbS, s);
}

__global__ __launch_bounds__(1024) void bscan1_k(
    const int* __restrict__ c, int* __restrict__ cur, int* __restrict__ sb, int nb) {
  __shared__ int s[1024];
  scan_dev(c, cur, sb, nb, s);
}

__global__ __launch_bounds__(256) void bscatter2_k(
    const int* __restrict__ kD, const int* __restrict__ kS,
    int* __restrict__ bcurD, int* __restrict__ bcurS,
    int2* __restrict__ sortedD, int2* __restrict__ sortedS, int E, int nbD, int nbS)
{
  __shared__ int hD[NBMAX], gbD[NBMAX], hS[NBMAX], gbS[NBMAX];
  __shared__ unsigned short lrD[EPB], lrS[EPB];
  for (int i = threadIdx.x; i < NBMAX; i += 256) { hD[i] = 0; hS[i] = 0; }
  __syncthreads();
  const int base = blockIdx.x * EPB;
  for (int i = threadIdx.x; i < EPB; i += 256) {
    const int e = base + i;
    if (e < E) {
      lrD[i] = (unsigned short)atomicAdd(&hD[kD[e] >> BSH], 1);
      lrS[i] = (unsigned short)atomicAdd(&hS[kS[e] >> BSH], 1);
    }
  }
  __syncthreads();
  for (int i = threadIdx.x; i < nbD; i += 256) if (hD[i]) gbD[i] = atomicAdd(&bcurD[i], hD[i]);
  for (int i = threadIdx.x; i < nbS; i += 256) if (hS[i]) gbS[i] = atomicAdd(&bcurS[i], hS[i]);
  __syncthreads();
  for (int i = threadIdx.x; i < EPB; i += 256) {
    const int e = base + i;
    if (e < E) {
      const int d = kD[e], s = kS[e];
      sortedD[gbD[d >> BSH] + lrD[i]] = make_int2(d, s);
      sortedS[gbS[s >> BSH] + lrS[i]] = make_int2(s, d);
    }
  }
}

__global__ __launch_bounds__(256) void bscatter_k(
    const int* __restrict__ key, const int* __restrict__ payload,
    int* __restrict__ bcur, int2* __restrict__ sorted, int E, int nb) {
  __shared__ int h[NBMAX];
  __shared__ int gb[NBMAX];
  __shared__ unsigned short lr[EPB];
  for (int i = threadIdx.x; i < NBMAX; i += 256) h[i] = 0;
  __syncthreads();
  const int base = blockIdx.x * EPB;
  for (int i = threadIdx.x; i < EPB; i += 256) {
    const int e = base + i;
    if (e < E) lr[i] = (unsigned short)atomicAdd(&h[key[e] >> BSH], 1);
  }
  __syncthreads();
  for (int i = threadIdx.x; i < nb; i += 256)
    if (h[i]) gb[i] = atomicAdd(&bcur[i], h[i]);
  __syncthreads();
  for (int i = threadIdx.x; i < EPB; i += 256) {
    const int e = base + i;
    if (e < E) {
      const int k = key[e];
      sorted[gb[k >> BSH] + lr[i]] = make_int2(k, payload[e]);
    }
  }
}

// one block per bucket: LDS degree histogram + scan -> rowptr; LDS-cursor fill
__global__ __launch_bounds__(256) void bfinish_k(
    const int2* __restrict__ sorted, const int* __restrict__ sbase,
    int* __restrict__ rp, int* __restrict__ ei, int Nn) {
  __shared__ int cnt[128];
  __shared__ int scn[128];
  const int b = blockIdx.x;
  const int node0 = b << BSH;
  const int e0 = sbase[b], e1 = sbase[b + 1];
  const int t = threadIdx.x;
  if (t < 128) cnt[t] = 0;
  __syncthreads();
  for (int e = e0 + t; e < e1; e += 256)
    atomicAdd(&cnt[sorted[e].x - node0], 1);
  __syncthreads();
  if (t < 128) scn[t] = cnt[t];
  __syncthreads();
#pragma unroll
  for (int off = 1; off < 128; off <<= 1) {
    int v = (t < 128 && t >= off) ? scn[t - off] : 0;
    __syncthreads();
    if (t < 128) scn[t] += v;
    __syncthreads();
  }
  const int nInB = (Nn - node0 < 128) ? (Nn - node0) : 128;
  int myexcl = 0;
  if (t < 128) myexcl = scn[t] - cnt[t];
  if (t < nInB) rp[node0 + t] = e0 + myexcl;
  if (b == (int)gridDim.x - 1 && t == 0) rp[Nn] = e1;
  __syncthreads();
  if (t < 128) cnt[t] = myexcl;
  __syncthreads();
  for (int e = e0 + t; e < e1; e += 256) {
    const int2 kp = sorted[e];
    const int p = atomicAdd(&cnt[kp.x - node0], 1);
    ei[e0 + p] = kp.y;
  }
}

// ===========================================================================
// Gathers over interleaved 512B rows [pooled_l1 | pooled_l2] (r7/r8-proven).
// 32 lanes per row; 16 edges (8KB) in flight per wave; one wave per dst node.
// ===========================================================================
__device__ __forceinline__ float4 fmax4(float4 a, float4 b) {
  return make_float4(fmaxf(a.x, b.x), fmaxf(a.y, b.y),
                     fmaxf(a.z, b.z), fmaxf(a.w, b.w));
}

__device__ __forceinline__ float4 gmax2_csr(const float4* __restrict__ t4,
                                            const int* __restrict__ rp,
                                            const int* __restrict__ ei,
                                            int n, int g, int sub) {
  const int p0 = rp[n], p1 = rp[n + 1];
  const float4 z = make_float4(0.f, 0.f, 0.f, 0.f);
  float4 m0 = z, m1 = z, m2 = z, m3 = z, m4 = z, m5 = z, m6 = z, m7 = z;
  if (p1 > p0) {
    const int last = p1 - 1;
    for (int p = p0; p < p1; p += 16) {
      int e0 = p + 0 + g;  e0 = e0 <= last ? e0 : last;
      int e1 = p + 2 + g;  e1 = e1 <= last ? e1 : last;
      int e2 = p + 4 + g;  e2 = e2 <= last ? e2 : last;
      int e3 = p + 6 + g;  e3 = e3 <= last ? e3 : last;
      int e4 = p + 8 + g;  e4 = e4 <= last ? e4 : last;
      int e5 = p + 10 + g; e5 = e5 <= last ? e5 : last;
      int e6 = p + 12 + g; e6 = e6 <= last ? e6 : last;
      int e7 = p + 14 + g; e7 = e7 <= last ? e7 : last;
      const int s0 = ei[e0], s1 = ei[e1], s2 = ei[e2], s3 = ei[e3];
      const int s4 = ei[e4], s5 = ei[e5], s6 = ei[e6], s7 = ei[e7];
      m0 = fmax4(m0, t4[(size_t)s0 * 32 + sub]);
      m1 = fmax4(m1, t4[(size_t)s1 * 32 + sub]);
      m2 = fmax4(m2, t4[(size_t)s2 * 32 + sub]);
      m3 = fmax4(m3, t4[(size_t)s3 * 32 + sub]);
      m4 = fmax4(m4, t4[(size_t)s4 * 32 + sub]);
      m5 = fmax4(m5, t4[(size_t)s5 * 32 + sub]);
      m6 = fmax4(m6, t4[(size_t)s6 * 32 + sub]);
      m7 = fmax4(m7, t4[(size_t)s7 * 32 + sub]);
    }
  }
  float4 m = fmax4(fmax4(fmax4(m0, m1), fmax4(m2, m3)),
                   fmax4(fmax4(m4, m5), fmax4(m6, m7)));
  m.x = fmaxf(m.x, __shfl_xor(m.x, 32));
  m.y = fmaxf(m.y, __shfl_xor(m.y, 32));
  m.z = fmaxf(m.z, __shfl_xor(m.z, 32));
  m.w = fmaxf(m.w, __shfl_xor(m.w, 32));
  return m;
}

// fwd: agg{1,2}[n] = maxVar + maxSoc (HeteroConv sums the two relations)
__global__ __launch_bounds__(256) void gather2f_k(
    const float4* __restrict__ t4,
    const int* __restrict__ rpCv, const int* __restrict__ eiCv,
    const int* __restrict__ rpCs, const int* __restrict__ eiCs,
    float4* __restrict__ agg1, float4* __restrict__ agg2, int N)
{
  const int lane = threadIdx.x & 63;
  const int g = lane >> 5, sub = lane & 31;
  const int n = __builtin_amdgcn_readfirstlane(blockIdx.x * 4 + (threadIdx.x >> 6));
  if (n >= N) return;
  const float4 a = gmax2_csr(t4, rpCv, eiCv, n, g, sub);
  const float4 b = gmax2_csr(t4 + (size_t)NV * 32, rpCs, eiCs, n, g, sub);
  const float4 r = make_float4(a.x + b.x, a.y + b.y, a.z + b.z, a.w + b.w);
  if (g == 0) {
    if (sub < 16) agg1[(size_t)n * 16 + sub] = r;
    else          agg2[(size_t)n * 16 + (sub - 16)] = r;
  }
}

// bwd (var only -- soc backward updates are dead code: output = MLP(h_var))
__global__ __launch_bounds__(256) void gatherB_k(
    const float4* __restrict__ t4,
    const int* __restrict__ rp, const int* __restrict__ ei,
    float4* __restrict__ agg1, float4* __restrict__ agg2, int N)
{
  const int lane = threadIdx.x & 63;
  const int g = lane >> 5, sub = lane & 31;
  const int n = __builtin_amdgcn_readfirstlane(blockIdx.x * 4 + (threadIdx.x >> 6));
  if (n >= N) return;
  const float4 m = gmax2_csr(t4, rp, ei, n, g, sub);
  if (g == 0) {
    if (sub < 16) agg1[(size_t)n * 16 + sub] = m;
    else          agg2[(size_t)n * 16 + (sub - 16)] = m;
  }
}

extern "C" void kernel_launch(void* const* d_in, const int* in_sizes, int n_in,
                              void* d_out, int out_size, void* d_ws, size_t ws_size,
                              hipStream_t stream) {
  const float* var_x = (const float*)d_in[0];
  const float* con_x = (const float*)d_in[1];
  const float* soc_x = (const float*)d_in[2];
  const float* W_var = (const float*)d_in[3];
  const float* b_var = (const float*)d_in[4];
  const float* W_con = (const float*)d_in[5];
  const float* b_con = (const float*)d_in[6];
  const float* W_soc = (const float*)d_in[7];
  const float* b_soc = (const float*)d_in[8];
  const float* L[4][5];  // L[0]=l1f, L[1]=l1b, L[2]=l2f, L[3]=l2b; 0=Wp 1=bp 2=Ws 3=Wn 4=b
  for (int l = 0; l < 4; ++l)
    for (int p = 0; p < 5; ++p)
      L[l][p] = (const float*)d_in[9 + l * 5 + p];
  const float* W_hid = (const float*)d_in[29];
  const float* b_hid = (const float*)d_in[30];
  const float* W_out = (const float*)d_in[31];
  const float* b_out = (const float*)d_in[32];
  const int* vc_src = (const int*)d_in[33];
  const int* vc_dst = (const int*)d_in[34];
  const int* sc_src = (const int*)d_in[35];
  const int* sc_dst = (const int*)d_in[36];

  char* ws = (char*)d_ws;
  const size_t SZ_HVS = (size_t)NVS * H * 4;      // 30.72 MB
  const size_t SZ_PF  = (size_t)NVS * 128 * 4;    // 61.44 MB
  const size_t SZ_AC  = (size_t)NC * H * 4;       // 25.6 MB
  const size_t SZ_PB  = (size_t)NC * 128 * 4;     // 51.2 MB
  float* h_vs    = (float*)ws;                          // var rows then soc rows
  float* pooledF = (float*)(ws + SZ_HVS);
  float* agg1b   = pooledF;                             // alias: pooledF dead after gather2f
  float* agg2b   = pooledF + (size_t)NV * H;
  float* agg1f   = (float*)(ws + SZ_HVS + SZ_PF);
  float* agg2f   = agg1f + (size_t)NC * H;
  float* h_con   = (float*)(ws + SZ_HVS + SZ_PF + 2 * SZ_AC);
  float* pooledB = (float*)(ws + SZ_HVS + SZ_PF + 3 * SZ_AC);
  int2*  sortedD = (int2*)pooledB;                      // alias: dead during builds
  int2*  sortedS = (int2*)((char*)pooledB + (size_t)EVC * 8);
  int* csr = (int*)(ws + SZ_HVS + SZ_PF + 3 * SZ_AC + SZ_PB);
  int* rpCv = csr;
  int* eiCv = rpCv + (NC + 1);
  int* rpCs = eiCv + EVC;
  int* eiCs = rpCs + (NC + 1);
  int* rpV  = eiCs + ESC;
  int* eiV  = rpV + (NV + 1);
  int* aux  = eiV + EVC;
  int* bcntD = aux;
  int* bcntS = aux + 1024;
  int* bcntC = aux + 2048;
  int* bcurD = aux + 3072;
  int* bcurS = aux + 4096;
  int* bcurC = aux + 5120;
  int* sbD   = aux + 6144;   // 1025 each, padded to 1056
  int* sbS   = sbD + 1056;
  int* sbC   = sbS + 1056;

  const int nbC = (NC + 127) >> BSH;   // 782
  const int nbV = (NV + 127) >> BSH;   // 782
  auto grid_l = [](int n) { return dim3((unsigned)((n + TR - 1) / TR)); };
  auto grid_w = [](int n) { return dim3((unsigned)((n + 3) / 4)); };
  auto grid_b = [](int e) { return dim3((unsigned)((e + EPB - 1) / EPB)); };
  const dim3 B(256);

  float* h_var = h_vs;                    // rows [0,NV)
  float* h_soc = h_vs + (size_t)NV * H;   // rows [NV,NVS)

  hipMemsetAsync(aux, 0, 3072 * sizeof(int), stream);  // the 3 bcnt arrays

  // ---- CSR builds: vc dual (dst & src keyed from ONE edge-list read) ------
  bhist2_k<<<grid_b(EVC), B, 0, stream>>>(vc_dst, vc_src, bcntD, bcntS, EVC, nbC, nbV);
  bscan2_k<<<dim3(1), dim3(1024), 0, stream>>>(bcntD, bcurD, sbD, nbC, bcntS, bcurS, sbS, nbV);
  bscatter2_k<<<grid_b(EVC), B, 0, stream>>>(vc_dst, vc_src, bcurD, bcurS, sortedD, sortedS, EVC, nbC, nbV);
  bfinish_k<<<dim3((unsigned)nbC), B, 0, stream>>>(sortedD, sbD, rpCv, eiCv, NC);
  bfinish_k<<<dim3((unsigned)nbV), B, 0, stream>>>(sortedS, sbS, rpV, eiV, NV);
  // sc: dst-keyed only (sc_src CSR is dead code)
  bhist_k<<<grid_b(ESC), B, 0, stream>>>(sc_dst, bcntC, ESC, nbC);
  bscan1_k<<<dim3(1), dim3(1024), 0, stream>>>(bcntC, bcurC, sbC, nbC);
  bscatter_k<<<grid_b(ESC), B, 0, stream>>>(sc_dst, sc_src, bcurC, sortedD, ESC, nbC);
  bfinish_k<<<dim3((unsigned)nbC), B, 0, stream>>>(sortedD, sbC, rpCs, eiCs, NC);

  // ---- embeddings ---------------------------------------------------------
  gemm_lds<7, 0, true, TR><<<grid_l(NV), B, 0, stream>>>(var_x, W_var, nullptr, nullptr, b_var, h_var, NV, 1.f);
  gemm_lds<4, 0, true, TR><<<grid_l(NC), B, 0, stream>>>(con_x, W_con, nullptr, nullptr, b_con, h_con, NC, 1.f);
  gemm_lds<6, 0, true, TR><<<grid_l(NSOC), B, 0, stream>>>(soc_x, W_soc, nullptr, nullptr, b_soc, h_soc, NSOC, 1.f);

  // ---- forward: dual pooled GEMM -> fused gather -> 2 in-place updates ----
  dualgemm_k<TR><<<grid_l(NVS), B, 0, stream>>>(h_vs, L[0][0], L[0][1], L[2][0], L[2][1], pooledF, NVS);
  gather2f_k<<<grid_w(NC), B, 0, stream>>>(
      (const float4*)pooledF, rpCv, eiCv, rpCs, eiCs,
      (float4*)agg1f, (float4*)agg2f, NC);
  gemm_lds<64, 1, true, TR><<<grid_l(NC), B, 0, stream>>>(h_con, L[0][2], agg1f, L[0][3], L[0][4], h_con, NC, 2.f);
  gemm_lds<64, 1, true, TR><<<grid_l(NC), B, 0, stream>>>(h_con, L[2][2], agg2f, L[2][3], L[2][4], h_con, NC, 2.f);

  // ---- backward: dual pooled GEMM -> var-only gather -> 2 in-place updates
  dualgemm_k<TR><<<grid_l(NC), B, 0, stream>>>(h_con, L[1][0], L[1][1], L[3][0], L[3][1], pooledB, NC);
  gatherB_k<<<grid_w(NV), B, 0, stream>>>(
      (const float4*)pooledB, rpV, eiV, (float4*)agg1b, (float4*)agg2b, NV);
  gemm_lds<64, 1, true, TR><<<grid_l(NV), B, 0, stream>>>(h_var, L[1][2], agg1b, L[1][3], L[1][4], h_var, NV, 1.f);
  gemm_lds<64, 1, true, TR><<<grid_l(NV), B, 0, stream>>>(h_var, L[3][2], agg2b, L[3][3], L[3][4], h_var, NV, 1.f);

  // ---- fused output MLP over var rows -------------------------------------
  mlp_k<TR><<<grid_l(NV), B, 0, stream>>>(h_var, W_hid, b_hid, W_out, b_out, (float*)d_out, NV);
}